// Round 6
// baseline (188.750 us; speedup 1.0000x reference)
//
#include <hip/hip_runtime.h>

// out[b] = M0 @ M1 @ ... @ M95  (4x4 fp32 chain per batch, left-to-right)
// Layout: mats[B][96][4][4] row-major fp32 = 384 float4 = 6144 B per batch.
//
// R6 = R5 with the build fixed: __builtin_nontemporal_load needs a NATIVE
// vector type, not HIP_vector_type. Use ext_vector_type(4) float for the
// nt loads/stores; everything else identical to R5 (R1 structure: 4 lanes
// per batch, one carry row per lane, DPP quad broadcasts, exact
// left-to-right order, prefetch depth 2, 32 waves/CU).

typedef float f4_t __attribute__((ext_vector_type(4)));

template <int CTRL>
__device__ __forceinline__ float dpp_mov(float x) {
    int xi = __builtin_bit_cast(int, x);
    int r = __builtin_amdgcn_update_dpp(0, xi, CTRL, 0xF, 0xF, true);
    return __builtin_bit_cast(float, r);
}

// Broadcast lane J (within each quad) of all 4 components of m.
template <int J>
__device__ __forceinline__ f4_t quad_bcast(f4_t m) {
    constexpr int C = J * 0x55;  // quad_perm:[J,J,J,J]
    f4_t r;
    r.x = dpp_mov<C>(m.x);
    r.y = dpp_mov<C>(m.y);
    r.z = dpp_mov<C>(m.z);
    r.w = dpp_mov<C>(m.w);
    return r;
}

// v = this lane's row of the carry; m = this lane's row of M.
__device__ __forceinline__ f4_t row_times_mat(f4_t v, f4_t m) {
    f4_t a = quad_bcast<0>(m);
    f4_t acc;
    acc.x = v.x * a.x; acc.y = v.x * a.y; acc.z = v.x * a.z; acc.w = v.x * a.w;
    a = quad_bcast<1>(m);
    acc.x = fmaf(v.y, a.x, acc.x); acc.y = fmaf(v.y, a.y, acc.y);
    acc.z = fmaf(v.y, a.z, acc.z); acc.w = fmaf(v.y, a.w, acc.w);
    a = quad_bcast<2>(m);
    acc.x = fmaf(v.z, a.x, acc.x); acc.y = fmaf(v.z, a.y, acc.y);
    acc.z = fmaf(v.z, a.z, acc.z); acc.w = fmaf(v.z, a.w, acc.w);
    a = quad_bcast<3>(m);
    acc.x = fmaf(v.w, a.x, acc.x); acc.y = fmaf(v.w, a.y, acc.y);
    acc.z = fmaf(v.w, a.z, acc.z); acc.w = fmaf(v.w, a.w, acc.w);
    return acc;
}

__device__ __forceinline__ f4_t ntload(const f4_t* p) {
    return __builtin_nontemporal_load(p);
}

__global__ __launch_bounds__(256, 8)
void chainmul_nt(const f4_t* __restrict__ mats, f4_t* __restrict__ out) {
    const int t = blockIdx.x * 256 + threadIdx.x;
    const int b = t >> 2;        // batch
    const int r = t & 3;         // carry row this lane owns
    const f4_t* p = mats + (size_t)b * 384 + r;

    f4_t v  = ntload(p);          // row r of M0 (initial carry)
    f4_t mA = ntload(p + 4);      // M1
    f4_t mB = ntload(p + 8);      // M2

    // iter n = 1,3,...,91: prefetch M_{n+2},M_{n+3}; apply M_n, M_{n+1}
#pragma unroll 2
    for (int n = 1; n <= 91; n += 2) {
        f4_t nA = ntload(p + (size_t)4 * (n + 2));
        f4_t nB = ntload(p + (size_t)4 * (n + 3));
        v = row_times_mat(v, mA);
        v = row_times_mat(v, mB);
        mA = nA;
        mB = nB;
    }
    // mA=M93, mB=M94; M95 remains
    f4_t mC = ntload(p + (size_t)4 * 95);
    v = row_times_mat(v, mA);
    v = row_times_mat(v, mB);
    v = row_times_mat(v, mC);

    __builtin_nontemporal_store(v, out + (size_t)b * 4 + r);
}

extern "C" void kernel_launch(void* const* d_in, const int* in_sizes, int n_in,
                              void* d_out, int out_size, void* d_ws, size_t ws_size,
                              hipStream_t stream) {
    const f4_t* mats = (const f4_t*)d_in[0];
    f4_t* out = (f4_t*)d_out;

    const int B = in_sizes[0] / (96 * 16);   // 131072
    const int threads = B * 4;
    const int block = 256;
    const int grid = threads / block;        // 2048 blocks
    hipLaunchKernelGGL(chainmul_nt, dim3(grid), dim3(block), 0, stream,
                       mats, out);
}

// Round 7
// 147.027 us; speedup vs baseline: 1.2838x; 1.2838x over previous
//
#include <hip/hip_runtime.h>

// out[b] = M0 @ M1 @ ... @ M95  (4x4 fp32 chain per batch, left-to-right)
// Layout: mats[B][96][4][4] row-major fp32 = 384 float4 per batch.
//
// FINAL (= R3, the measured best at 146.6 us = 5.5 TB/s pure read):
//   - 4 lanes per batch (lane owns one carry row), DPP quad broadcasts,
//     exact left-to-right multiply order (absmax 0.0).
//   - 4-matrix supersteps staged to LDS via global_load_lds width=16
//     (256 B contiguous per batch per superstep).
//   - LDS 32 KB/block -> 5 blocks/CU -> 20 waves/CU.
//   - double-buffered, counted s_waitcnt vmcnt(4), no barriers
//     (each wave owns its LDS region exclusively).
//   - slot swizzle (s ^ (bl&15)) applied on the per-lane SOURCE address
//     (global_load_lds LDS dest must stay linear), undone on the ds_read
//     side: 2 lanes/bank = conflict-free.
//
// Roofline argument: 805 MB read + 8 MB write is the information-theoretic
// floor (every input byte participates in its chain product). Measured
// pure-read ceiling on this part is ~5.5 TB/s (five structural variants
// spanning 64B-6KB request contiguity, 8-32 waves/CU, direct/LDS/register
// staging all land 146-152 us; nt policy regresses 24%). 813 MB / 5.5 TB/s
// ~= 147 us = this kernel.

typedef const void __attribute__((address_space(1))) gvoid_t;
typedef void __attribute__((address_space(3))) lvoid_t;

#define GLOAD_LDS16(g, l) \
    __builtin_amdgcn_global_load_lds((gvoid_t*)(g), (lvoid_t*)(l), 16, 0, 0)

template <int CTRL>
__device__ __forceinline__ float dpp_mov(float x) {
    int xi = __builtin_bit_cast(int, x);
    int r = __builtin_amdgcn_update_dpp(0, xi, CTRL, 0xF, 0xF, true);
    return __builtin_bit_cast(float, r);
}

// Broadcast lane J (within each quad) of all 4 components of m.
template <int J>
__device__ __forceinline__ float4 quad_bcast(float4 m) {
    constexpr int C = J * 0x55;  // quad_perm:[J,J,J,J]
    float4 r;
    r.x = dpp_mov<C>(m.x);
    r.y = dpp_mov<C>(m.y);
    r.z = dpp_mov<C>(m.z);
    r.w = dpp_mov<C>(m.w);
    return r;
}

// v = this lane's row of the carry; m = this lane's row of M.
// Returns this lane's row of carry @ M (rows of M broadcast via DPP).
__device__ __forceinline__ float4 row_times_mat(float4 v, float4 m) {
    float4 a = quad_bcast<0>(m);
    float4 acc;
    acc.x = v.x * a.x; acc.y = v.x * a.y; acc.z = v.x * a.z; acc.w = v.x * a.w;
    a = quad_bcast<1>(m);
    acc.x = fmaf(v.y, a.x, acc.x); acc.y = fmaf(v.y, a.y, acc.y);
    acc.z = fmaf(v.y, a.z, acc.z); acc.w = fmaf(v.y, a.w, acc.w);
    a = quad_bcast<2>(m);
    acc.x = fmaf(v.z, a.x, acc.x); acc.y = fmaf(v.z, a.y, acc.y);
    acc.z = fmaf(v.z, a.z, acc.z); acc.w = fmaf(v.z, a.w, acc.w);
    a = quad_bcast<3>(m);
    acc.x = fmaf(v.w, a.x, acc.x); acc.y = fmaf(v.w, a.y, acc.y);
    acc.z = fmaf(v.w, a.z, acc.z); acc.w = fmaf(v.w, a.w, acc.w);
    return acc;
}

__global__ __launch_bounds__(256)
void chainmul_staged4(const float4* __restrict__ mats, float4* __restrict__ out) {
    // [wave 4][buf 2][instr 4][lane 64] float4 = 32 KB
    __shared__ float4 stage[2048];

    const int tid  = threadIdx.x;
    const int wave = tid >> 6;
    const int lane = tid & 63;
    const int q    = lane >> 2;   // batch-in-wave (compute role)
    const int r    = lane & 3;    // carry row this lane owns
    const int wb0  = blockIdx.x * 64 + wave * 16;  // wave's first batch

    // --- staging roles: instr i covers batches 4i..4i+3 of this wave ---
    const int blo = lane >> 4;    // batch within the instr's group of 4
    const int sp  = lane & 15;    // physical slot within the 256 B slice

    int src_base[4];              // float4 index into mats, per instr
#pragma unroll
    for (int i = 0; i < 4; ++i) {
        const int bl = 4 * i + blo;
        // phys slot sp holds logical slot (sp ^ (bl&15))  [source-side swizzle]
        src_base[i] = (wb0 + bl) * 384 + (sp ^ (bl & 15));
    }

    float4* const wlds = &stage[wave * 512];  // this wave's 8 KB region

    // prologue: stage superstep 0 (matrices 0..3) into buf 0
#pragma unroll
    for (int i = 0; i < 4; ++i)
        GLOAD_LDS16(mats + src_base[i], wlds + i * 64);

    // carry = row r of identity (first multiply is exact: 1*x + 0*y)
    float4 v = make_float4(r == 0 ? 1.0f : 0.0f, r == 1 ? 1.0f : 0.0f,
                           r == 2 ? 1.0f : 0.0f, r == 3 ? 1.0f : 0.0f);

    for (int t = 0; t < 24; ++t) {            // 24 supersteps x 4 matrices
        const int buf = t & 1;
        if (t < 23) {
            float4* const dst = wlds + (buf ^ 1) * 256;
            const int off = (t + 1) * 16;
#pragma unroll
            for (int i = 0; i < 4; ++i)
                GLOAD_LDS16(mats + src_base[i] + off, dst + i * 64);
            // keep next-superstep loads in flight; wait only for current's
            asm volatile("s_waitcnt vmcnt(4)" ::: "memory");
        } else {
            asm volatile("s_waitcnt vmcnt(0)" ::: "memory");
        }

        const float4* const cbuf = wlds + buf * 256 + q * 16;
#pragma unroll
        for (int m = 0; m < 4; ++m) {
            // undo the source-side swizzle
            const float4 row = cbuf[(m * 4 + r) ^ (q & 15)];
            v = row_times_mat(v, row);
        }
    }

    out[(size_t)(wb0 + q) * 4 + r] = v;  // 64 B per quad, coalesced
}

extern "C" void kernel_launch(void* const* d_in, const int* in_sizes, int n_in,
                              void* d_out, int out_size, void* d_ws, size_t ws_size,
                              hipStream_t stream) {
    const float4* mats = (const float4*)d_in[0];
    float4* out = (float4*)d_out;

    const int B = in_sizes[0] / (96 * 16);   // 131072
    const int grid = B / 64;                 // 64 batches per 256-thread block
    hipLaunchKernelGGL(chainmul_staged4, dim3(grid), dim3(256), 0, stream,
                       mats, out);
}